// Round 5
// baseline (152.443 us; speedup 1.0000x reference)
//
#include <hip/hip_runtime.h>
#include <hip/hip_bf16.h>

typedef short bf16x8 __attribute__((ext_vector_type(8)));
typedef float f32x4 __attribute__((ext_vector_type(4)));

#define N_NODES 1024
#define FDIM 64
#define NG 32   // B * Tp = 2 * 16
#define LOG2E 1.44269504088896f

// ---------------- K0: expand adjacency into additive bf16 mask ----------------
__global__ __launch_bounds__(256) void k_maskf(const int* __restrict__ adj,
                                               __hip_bfloat16* __restrict__ Madd) {
    int w = blockIdx.x * 256 + threadIdx.x;      // 32768 threads, 32 els each
    const int* p = adj + (size_t)w * 32;
    union { bf16x8 v[4]; __hip_bfloat16 hh[32]; } u;
#pragma unroll
    for (int b = 0; b < 32; b++)
        u.hh[b] = __float2bfloat16(p[b] > 0 ? 0.f : -2048.f);
    bf16x8* dst = (bf16x8*)(Madd + (size_t)w * 32);
#pragma unroll
    for (int q = 0; q < 4; q++) dst[q] = u.v[q];
}

// ---------------- K1: layer-1 projection + score vectors (×log2e) ----------------
__global__ __launch_bounds__(256) void k_proj1(const float* __restrict__ x,
                                               const float* __restrict__ Wh,
                                               const float* __restrict__ ah,
                                               __hip_bfloat16* __restrict__ H1T,
                                               float* __restrict__ F1,
                                               float* __restrict__ F2) {
    __shared__ float xs[64][68];
    __shared__ float ws[64][64];
    const int t = threadIdx.x;
    const int nt = blockIdx.x, g = blockIdx.y, h = blockIdx.z;
    const int n0 = nt * 64;
    const int b = g >> 4, tstep = g & 15;
    const int r = t >> 2, cq = t & 3;

    const float* xrow = x + (((size_t)(b * 17 + tstep) * N_NODES + n0 + r) * FDIM);
    const float4* xsrc = (const float4*)(xrow + cq * 16);
#pragma unroll
    for (int q = 0; q < 4; q++) *(float4*)&xs[r][cq * 16 + q * 4] = xsrc[q];
    const float4* wsrc = (const float4*)(Wh + (size_t)h * 4096 + (size_t)r * 64 + cq * 16);
#pragma unroll
    for (int q = 0; q < 4; q++) *(float4*)&ws[r][cq * 16 + q * 4] = wsrc[q];
    __syncthreads();

    float acc[16];
#pragma unroll
    for (int c = 0; c < 16; c++) acc[c] = 0.f;
    for (int k = 0; k < 64; k++) {
        float a = xs[r][k];
        const float* wr = &ws[k][cq * 16];
#pragma unroll
        for (int c = 0; c < 16; c++) acc[c] = fmaf(a, wr[c], acc[c]);
    }

    const float* a1 = ah + h * 128;
    float p1 = 0.f, p2 = 0.f;
#pragma unroll
    for (int c = 0; c < 16; c++) {
        p1 = fmaf(acc[c], a1[cq * 16 + c], p1);
        p2 = fmaf(acc[c], a1[64 + cq * 16 + c], p2);
    }
    p1 += __shfl_xor(p1, 1); p1 += __shfl_xor(p1, 2);
    p2 += __shfl_xor(p2, 1); p2 += __shfl_xor(p2, 2);
    const int n = n0 + r;
    const size_t gh = (size_t)h * NG + g;
    if (cq == 0) {
        F1[gh * N_NODES + n] = p1 * LOG2E;
        F2[gh * N_NODES + n] = p2 * LOG2E;
    }
    __hip_bfloat16* Hb = H1T + gh * FDIM * N_NODES;
#pragma unroll
    for (int c = 0; c < 16; c++)
        Hb[(size_t)(cq * 16 + c) * N_NODES + n] = __float2bfloat16(acc[c]);
}

// ---------------- fused masked attention ----------------
// 128 rows/block, 8 waves x 16 rows; j-tile 256 single-buffered in LDS with
// XOR-swizzled 16B units; f2 + mask streamed from global with 1-jc-ahead
// prefetch (no LDS broadcast conflicts); row-sum via ones-MFMA.
template<int CONCAT>
__global__ __launch_bounds__(512, 4) void k_attn(
    const __hip_bfloat16* __restrict__ HT,   // [G][64 f][1024 n] bf16
    const float* __restrict__ F1,            // [G][1024] (×log2e)
    const float* __restrict__ F2,
    const __hip_bfloat16* __restrict__ Madd, // [1024][1024] additive mask
    __hip_bfloat16* __restrict__ HC,         // concat out (CONCAT=1)
    float* __restrict__ out)                 // final out (CONCAT=0)
{
    __shared__ __hip_bfloat16 vt[64][256];   // linear rows; unit-XOR swizzle
    const int t = threadIdx.x;
    const int nb = blockIdx.x, g = blockIdx.y, h = blockIdx.z;
    const int i0 = nb * 128;
    const size_t gidx = CONCAT ? ((size_t)h * NG + g) : (size_t)g;

    const int wv = t >> 6, ln = t & 63;
    const int li = ln & 15, grp = ln >> 4, jb = grp * 8;
    const int lx = li & 7;
    const int il = wv * 16 + li;
    const float f1v = F1[gidx * N_NODES + i0 + il];

    const __hip_bfloat16* Hg = HT + gidx * (size_t)(FDIM * N_NODES);
    const int srow = wv * 8 + (ln >> 3);          // staging row (f)
    const int swu = (ln & 7) ^ (srow & 7);        // swizzled low-3 unit
    const __hip_bfloat16* srcb = Hg + (size_t)srow * N_NODES + (ln & 7) * 8;
    const __hip_bfloat16* Mp = Madd + (size_t)(i0 + il) * N_NODES + jb;
    const float* f2p = F2 + gidx * N_NODES + jb;

    f32x4 acc[4], acc5;
#pragma unroll
    for (int q = 0; q < 4; q++) acc[q] = (f32x4){0.f, 0.f, 0.f, 0.f};
    acc5 = (f32x4){0.f, 0.f, 0.f, 0.f};

    union { bf16x8 v; short s[8]; } onesu;
#pragma unroll
    for (int q = 0; q < 8; q++) onesu.s[q] = (short)0x3F80;  // bf16 1.0
    const bf16x8 ones = onesu.v;

    bf16x8 stg[4];
#pragma unroll
    for (int k2 = 0; k2 < 4; k2++) stg[k2] = *(const bf16x8*)(srcb + k2 * 64);
    float4 fa = *(const float4*)f2p;
    float4 fb = *(const float4*)(f2p + 4);
    bf16x8 mreg = *(const bf16x8*)Mp;

    for (int jt = 0; jt < 4; jt++) {
        __syncthreads();                      // all waves done reading vt
#pragma unroll
        for (int k2 = 0; k2 < 4; k2++)
            *(bf16x8*)&vt[srow][(k2 * 8 + swu) * 8] = stg[k2];
        if (jt < 3) {                         // issue next tile's global loads
#pragma unroll
            for (int k2 = 0; k2 < 4; k2++)
                stg[k2] = *(const bf16x8*)(srcb + (jt + 1) * 256 + k2 * 64);
        }
        __syncthreads();                      // vt fully written

#pragma unroll
        for (int jc = 0; jc < 8; jc++) {
            float f2a[8] = {fa.x, fa.y, fa.z, fa.w, fb.x, fb.y, fb.z, fb.w};
            union { bf16x8 v; unsigned u[4]; } mc;
            mc.v = mreg;
            if (!(jt == 3 && jc == 7)) {      // prefetch next jc (linear cols)
                fa = *(const float4*)(f2p + 32);
                fb = *(const float4*)(f2p + 36);
                mreg = *(const bf16x8*)(Mp + 32);
            }
            f2p += 32; Mp += 32;

            union { bf16x8 v; __hip_bfloat16 hh[8]; } afr;
#pragma unroll
            for (int d = 0; d < 4; d++) {
                float mlo = __uint_as_float(mc.u[d] << 16);
                float mhi = __uint_as_float(mc.u[d] & 0xffff0000u);
                float s0 = f1v + f2a[2 * d] + mlo;       // v_add3
                float s1 = f1v + f2a[2 * d + 1] + mhi;
                s0 = fmaxf(s0, 0.2f * s0);               // LeakyReLU
                s1 = fmaxf(s1, 0.2f * s1);
                float p0 = __builtin_amdgcn_exp2f(s0);
                float p1 = __builtin_amdgcn_exp2f(s1);
                afr.hh[2 * d]     = __float2bfloat16(p0);
                afr.hh[2 * d + 1] = __float2bfloat16(p1);
            }
            // swizzled B-frag read: unit = jc*4+grp, low3 XOR li&7
            const int ub = (jc >> 1) * 8 + (((jc & 1) * 4 + grp) ^ lx);
#pragma unroll
            for (int q = 0; q < 4; q++) {
                bf16x8 bfr = *(const bf16x8*)&vt[q * 16 + li][ub * 8];
                acc[q] = __builtin_amdgcn_mfma_f32_16x16x32_bf16(afr.v, bfr, acc[q], 0, 0, 0);
            }
            acc5 = __builtin_amdgcn_mfma_f32_16x16x32_bf16(afr.v, ones, acc5, 0, 0, 0);
        }
    }

    float rin[4];
#pragma unroll
    for (int r2 = 0; r2 < 4; r2++) rin[r2] = 1.0f / acc5[r2];

    if (CONCAT) {
        __hip_bfloat16* HCg = HC + (size_t)g * N_NODES * 256 + h * 64;
#pragma unroll
        for (int q = 0; q < 4; q++)
#pragma unroll
            for (int r2 = 0; r2 < 4; r2++) {
                int irow = wv * 16 + grp * 4 + r2;
                float v = acc[q][r2] * rin[r2];
                v = v > 0.f ? v : expm1f(v); // ELU
                HCg[(size_t)(i0 + irow) * 256 + q * 16 + li] = __float2bfloat16(v);
            }
    } else {
        float* og = out + (size_t)g * N_NODES * FDIM;
#pragma unroll
        for (int q = 0; q < 4; q++)
#pragma unroll
            for (int r2 = 0; r2 < 4; r2++) {
                int irow = wv * 16 + grp * 4 + r2;
                float v = acc[q][r2] * rin[r2];
                og[(size_t)(i0 + irow) * FDIM + q * 16 + li] = v > 0.f ? v : 0.f;
            }
    }
}

// ---------------- K3: layer-2 projection + score vectors ----------------
__global__ __launch_bounds__(256) void k_proj2(const __hip_bfloat16* __restrict__ HC,
                                               const float* __restrict__ Wo,
                                               const float* __restrict__ ao,
                                               __hip_bfloat16* __restrict__ H2T,
                                               float* __restrict__ F1b,
                                               float* __restrict__ F2b) {
    __shared__ float xs[64][68];
    __shared__ float ws[64][64];
    const int t = threadIdx.x;
    const int nt = blockIdx.x, g = blockIdx.y;
    const int n0 = nt * 64;
    const int r = t >> 2, cq = t & 3;
    float acc[16];
#pragma unroll
    for (int c = 0; c < 16; c++) acc[c] = 0.f;

    for (int k0 = 0; k0 < 256; k0 += 64) {
        const __hip_bfloat16* src = HC + ((size_t)g * N_NODES + n0 + r) * 256 + k0 + cq * 16;
        union { bf16x8 v; __hip_bfloat16 hh[8]; } u0, u1;
        u0.v = *(const bf16x8*)(src);
        u1.v = *(const bf16x8*)(src + 8);
#pragma unroll
        for (int c = 0; c < 8; c++) {
            xs[r][cq * 16 + c] = __bfloat162float(u0.hh[c]);
            xs[r][cq * 16 + 8 + c] = __bfloat162float(u1.hh[c]);
        }
        const float4* wsrc = (const float4*)(Wo + (size_t)(k0 + r) * 64 + cq * 16);
#pragma unroll
        for (int q = 0; q < 4; q++) *(float4*)&ws[r][cq * 16 + q * 4] = wsrc[q];
        __syncthreads();
        for (int k = 0; k < 64; k++) {
            float a = xs[r][k];
            const float* wr = &ws[k][cq * 16];
#pragma unroll
            for (int c = 0; c < 16; c++) acc[c] = fmaf(a, wr[c], acc[c]);
        }
        __syncthreads();
    }

    float p1 = 0.f, p2 = 0.f;
#pragma unroll
    for (int c = 0; c < 16; c++) {
        p1 = fmaf(acc[c], ao[cq * 16 + c], p1);
        p2 = fmaf(acc[c], ao[64 + cq * 16 + c], p2);
    }
    p1 += __shfl_xor(p1, 1); p1 += __shfl_xor(p1, 2);
    p2 += __shfl_xor(p2, 1); p2 += __shfl_xor(p2, 2);
    const int n = n0 + r;
    if (cq == 0) {
        F1b[(size_t)g * N_NODES + n] = p1 * LOG2E;
        F2b[(size_t)g * N_NODES + n] = p2 * LOG2E;
    }
    __hip_bfloat16* Hb = H2T + (size_t)g * FDIM * N_NODES;
#pragma unroll
    for (int c = 0; c < 16; c++)
        Hb[(size_t)(cq * 16 + c) * N_NODES + n] = __float2bfloat16(acc[c]);
}

extern "C" void kernel_launch(void* const* d_in, const int* in_sizes, int n_in,
                              void* d_out, int out_size, void* d_ws, size_t ws_size,
                              hipStream_t stream) {
    const float* x  = (const float*)d_in[0];
    const int* adj  = (const int*)d_in[1];
    const float* Wh = (const float*)d_in[2];
    const float* ah = (const float*)d_in[3];
    const float* Wo = (const float*)d_in[4];
    const float* ao = (const float*)d_in[5];

    char* ws = (char*)d_ws;
    __hip_bfloat16* Madd = (__hip_bfloat16*)(ws);                  // 2 MB
    float* F1  = (float*)(ws + 2097152);                           // 512 KB
    float* F2  = (float*)(ws + 2621440);                           // 512 KB
    float* F1b = (float*)(ws + 3145728);                           // 128 KB
    float* F2b = (float*)(ws + 3276800);                           // 128 KB
    __hip_bfloat16* H1T = (__hip_bfloat16*)(ws + 3407872);             // 16 MB
    __hip_bfloat16* HC  = (__hip_bfloat16*)(ws + 3407872 + 16777216);  // 16 MB
    __hip_bfloat16* H2T = (__hip_bfloat16*)(ws + 3407872 + 33554432);  //  4 MB
    float* out = (float*)d_out;

    k_maskf  <<<dim3(128),       dim3(256), 0, stream>>>(adj, Madd);
    k_proj1  <<<dim3(16, 32, 4), dim3(256), 0, stream>>>(x, Wh, ah, H1T, F1, F2);
    k_attn<1><<<dim3(8, 32, 4),  dim3(512), 0, stream>>>(H1T, F1, F2, Madd, HC, nullptr);
    k_proj2  <<<dim3(16, 32),    dim3(256), 0, stream>>>(HC, Wo, ao, H2T, F1b, F2b);
    k_attn<0><<<dim3(8, 32, 1),  dim3(512), 0, stream>>>(H2T, F1b, F2b, Madd, nullptr, out);
}

// Round 6
// 126.296 us; speedup vs baseline: 1.2070x; 1.2070x over previous
//
#include <hip/hip_runtime.h>
#include <hip/hip_bf16.h>

typedef short bf16x8 __attribute__((ext_vector_type(8)));
typedef float f32x4 __attribute__((ext_vector_type(4)));

#define N_NODES 1024
#define FDIM 64
#define NG 32   // B * Tp = 2 * 16
#define LOG2E 1.44269504088896f

// ---------------- K0: expand adjacency into additive bf16 mask ----------------
__global__ __launch_bounds__(256) void k_maskf(const int* __restrict__ adj,
                                               __hip_bfloat16* __restrict__ Madd) {
    int w = blockIdx.x * 256 + threadIdx.x;      // 32768 threads, 32 els each
    const int* p = adj + (size_t)w * 32;
    union { bf16x8 v[4]; __hip_bfloat16 hh[32]; } u;
#pragma unroll
    for (int b = 0; b < 32; b++)
        u.hh[b] = __float2bfloat16(p[b] > 0 ? 0.f : -2048.f);
    bf16x8* dst = (bf16x8*)(Madd + (size_t)w * 32);
#pragma unroll
    for (int q = 0; q < 4; q++) dst[q] = u.v[q];
}

// ---------------- K1: layer-1 projection + score vectors (×log2e) ----------------
__global__ __launch_bounds__(256) void k_proj1(const float* __restrict__ x,
                                               const float* __restrict__ Wh,
                                               const float* __restrict__ ah,
                                               __hip_bfloat16* __restrict__ H1T,
                                               float* __restrict__ F1,
                                               float* __restrict__ F2) {
    __shared__ float xs[64][68];
    __shared__ float ws[64][64];
    const int t = threadIdx.x;
    const int nt = blockIdx.x, g = blockIdx.y, h = blockIdx.z;
    const int n0 = nt * 64;
    const int b = g >> 4, tstep = g & 15;
    const int r = t >> 2, cq = t & 3;

    const float* xrow = x + (((size_t)(b * 17 + tstep) * N_NODES + n0 + r) * FDIM);
    const float4* xsrc = (const float4*)(xrow + cq * 16);
#pragma unroll
    for (int q = 0; q < 4; q++) *(float4*)&xs[r][cq * 16 + q * 4] = xsrc[q];
    const float4* wsrc = (const float4*)(Wh + (size_t)h * 4096 + (size_t)r * 64 + cq * 16);
#pragma unroll
    for (int q = 0; q < 4; q++) *(float4*)&ws[r][cq * 16 + q * 4] = wsrc[q];
    __syncthreads();

    float acc[16];
#pragma unroll
    for (int c = 0; c < 16; c++) acc[c] = 0.f;
    for (int k = 0; k < 64; k++) {
        float a = xs[r][k];
        const float* wr = &ws[k][cq * 16];
#pragma unroll
        for (int c = 0; c < 16; c++) acc[c] = fmaf(a, wr[c], acc[c]);
    }

    const float* a1 = ah + h * 128;
    float p1 = 0.f, p2 = 0.f;
#pragma unroll
    for (int c = 0; c < 16; c++) {
        p1 = fmaf(acc[c], a1[cq * 16 + c], p1);
        p2 = fmaf(acc[c], a1[64 + cq * 16 + c], p2);
    }
    p1 += __shfl_xor(p1, 1); p1 += __shfl_xor(p1, 2);
    p2 += __shfl_xor(p2, 1); p2 += __shfl_xor(p2, 2);
    const int n = n0 + r;
    const size_t gh = (size_t)h * NG + g;
    if (cq == 0) {
        F1[gh * N_NODES + n] = p1 * LOG2E;
        F2[gh * N_NODES + n] = p2 * LOG2E;
    }
    __hip_bfloat16* Hb = H1T + gh * FDIM * N_NODES;
#pragma unroll
    for (int c = 0; c < 16; c++)
        Hb[(size_t)(cq * 16 + c) * N_NODES + n] = __float2bfloat16(acc[c]);
}

// ---------------- fused masked attention ----------------
// 128 rows/block, 8 waves x 16 rows; j-tile 256 single-buffered in LDS with
// XOR-swizzled 16B units; f2 in LDS; mask streamed (2-jc-deep prefetch);
// row-sum via ones-MFMA. Grid = (g, h, nb): slab-sharing blocks co-XCD.
template<int CONCAT>
__global__ __launch_bounds__(512, 4) void k_attn(
    const __hip_bfloat16* __restrict__ HT,   // [G][64 f][1024 n] bf16
    const float* __restrict__ F1,            // [G][1024] (×log2e)
    const float* __restrict__ F2,
    const __hip_bfloat16* __restrict__ Madd, // [1024][1024] additive mask
    __hip_bfloat16* __restrict__ HC,         // concat out (CONCAT=1)
    float* __restrict__ out)                 // final out (CONCAT=0)
{
    __shared__ __hip_bfloat16 vt[64][256];   // linear rows; unit-XOR swizzle
    __shared__ float f2s[N_NODES];
    const int t = threadIdx.x;
    const int g = blockIdx.x, h = blockIdx.y, nb = blockIdx.z;
    const int i0 = nb * 128;
    const size_t gidx = CONCAT ? ((size_t)h * NG + g) : (size_t)g;

    ((float2*)f2s)[t] = ((const float2*)(F2 + gidx * N_NODES))[t];

    const int wv = t >> 6, ln = t & 63;
    const int li = ln & 15, grp = ln >> 4, jb = grp * 8;
    const int lx = li & 7;
    const int il = wv * 16 + li;
    const float f1v = F1[gidx * N_NODES + i0 + il];

    const __hip_bfloat16* Hg = HT + gidx * (size_t)(FDIM * N_NODES);
    const int srow = wv * 8 + (ln >> 3);          // staging row (f)
    const int swu = (ln & 7) ^ (srow & 7);        // swizzled low-3 unit
    const __hip_bfloat16* srcb = Hg + (size_t)srow * N_NODES + (ln & 7) * 8;
    const __hip_bfloat16* Mp = Madd + (size_t)(i0 + il) * N_NODES + jb;

    f32x4 acc[4], acc5;
#pragma unroll
    for (int q = 0; q < 4; q++) acc[q] = (f32x4){0.f, 0.f, 0.f, 0.f};
    acc5 = (f32x4){0.f, 0.f, 0.f, 0.f};

    union { bf16x8 v; short s[8]; } onesu;
#pragma unroll
    for (int q = 0; q < 8; q++) onesu.s[q] = (short)0x3F80;  // bf16 1.0
    const bf16x8 ones = onesu.v;

    bf16x8 stg[4];
#pragma unroll
    for (int k2 = 0; k2 < 4; k2++) stg[k2] = *(const bf16x8*)(srcb + k2 * 64);
    bf16x8 m0 = *(const bf16x8*)Mp;               // 2-deep mask prefetch
    bf16x8 m1 = *(const bf16x8*)(Mp + 32);

    for (int jt = 0; jt < 4; jt++) {
        __syncthreads();                      // all waves done reading vt
#pragma unroll
        for (int k2 = 0; k2 < 4; k2++)
            *(bf16x8*)&vt[srow][(k2 * 8 + swu) * 8] = stg[k2];
        if (jt < 3) {                         // issue next tile's global loads
#pragma unroll
            for (int k2 = 0; k2 < 4; k2++)
                stg[k2] = *(const bf16x8*)(srcb + (jt + 1) * 256 + k2 * 64);
        }
        __syncthreads();                      // vt fully written

#pragma unroll
        for (int jc = 0; jc < 8; jc++) {
            union { bf16x8 v; unsigned u[4]; } mc;
            mc.v = m0;
            m0 = m1;
            if (!(jt == 3 && jc >= 6))        // rotate 2-deep prefetch
                m1 = *(const bf16x8*)(Mp + 64);
            Mp += 32;

            const float* f2p = &f2s[jt * 256 + jc * 32 + jb];
            float4 fa = *(const float4*)f2p;
            float4 fb = *(const float4*)(f2p + 4);
            float f2a[8] = {fa.x, fa.y, fa.z, fa.w, fb.x, fb.y, fb.z, fb.w};
            union { bf16x8 v; __hip_bfloat16 hh[8]; } afr;
#pragma unroll
            for (int d = 0; d < 4; d++) {
                float mlo = __uint_as_float(mc.u[d] << 16);
                float mhi = __uint_as_float(mc.u[d] & 0xffff0000u);
                float s0 = f1v + f2a[2 * d] + mlo;       // v_add3
                float s1 = f1v + f2a[2 * d + 1] + mhi;
                s0 = fmaxf(s0, 0.2f * s0);               // LeakyReLU
                s1 = fmaxf(s1, 0.2f * s1);
                float p0 = __builtin_amdgcn_exp2f(s0);
                float p1 = __builtin_amdgcn_exp2f(s1);
                afr.hh[2 * d]     = __float2bfloat16(p0);
                afr.hh[2 * d + 1] = __float2bfloat16(p1);
            }
            // swizzled B-frag read: unit = jc*4+grp, low3 XOR li&7
            const int ub = (jc >> 1) * 8 + (((jc & 1) * 4 + grp) ^ lx);
#pragma unroll
            for (int q = 0; q < 4; q++) {
                bf16x8 bfr = *(const bf16x8*)&vt[q * 16 + li][ub * 8];
                acc[q] = __builtin_amdgcn_mfma_f32_16x16x32_bf16(afr.v, bfr, acc[q], 0, 0, 0);
            }
            acc5 = __builtin_amdgcn_mfma_f32_16x16x32_bf16(afr.v, ones, acc5, 0, 0, 0);
        }
    }

    float rin[4];
#pragma unroll
    for (int r2 = 0; r2 < 4; r2++) rin[r2] = 1.0f / acc5[r2];

    if (CONCAT) {
        __hip_bfloat16* HCg = HC + (size_t)g * N_NODES * 256 + h * 64;
#pragma unroll
        for (int q = 0; q < 4; q++)
#pragma unroll
            for (int r2 = 0; r2 < 4; r2++) {
                int irow = wv * 16 + grp * 4 + r2;
                float v = acc[q][r2] * rin[r2];
                v = v > 0.f ? v : expm1f(v); // ELU
                HCg[(size_t)(i0 + irow) * 256 + q * 16 + li] = __float2bfloat16(v);
            }
    } else {
        float* og = out + (size_t)g * N_NODES * FDIM;
#pragma unroll
        for (int q = 0; q < 4; q++)
#pragma unroll
            for (int r2 = 0; r2 < 4; r2++) {
                int irow = wv * 16 + grp * 4 + r2;
                float v = acc[q][r2] * rin[r2];
                og[(size_t)(i0 + irow) * FDIM + q * 16 + li] = v > 0.f ? v : 0.f;
            }
    }
}

// ---------------- K3: layer-2 projection + score vectors ----------------
__global__ __launch_bounds__(256) void k_proj2(const __hip_bfloat16* __restrict__ HC,
                                               const float* __restrict__ Wo,
                                               const float* __restrict__ ao,
                                               __hip_bfloat16* __restrict__ H2T,
                                               float* __restrict__ F1b,
                                               float* __restrict__ F2b) {
    __shared__ float xs[64][68];
    __shared__ float ws[64][64];
    const int t = threadIdx.x;
    const int nt = blockIdx.x, g = blockIdx.y;
    const int n0 = nt * 64;
    const int r = t >> 2, cq = t & 3;
    float acc[16];
#pragma unroll
    for (int c = 0; c < 16; c++) acc[c] = 0.f;

    for (int k0 = 0; k0 < 256; k0 += 64) {
        const __hip_bfloat16* src = HC + ((size_t)g * N_NODES + n0 + r) * 256 + k0 + cq * 16;
        union { bf16x8 v; __hip_bfloat16 hh[8]; } u0, u1;
        u0.v = *(const bf16x8*)(src);
        u1.v = *(const bf16x8*)(src + 8);
#pragma unroll
        for (int c = 0; c < 8; c++) {
            xs[r][cq * 16 + c] = __bfloat162float(u0.hh[c]);
            xs[r][cq * 16 + 8 + c] = __bfloat162float(u1.hh[c]);
        }
        const float4* wsrc = (const float4*)(Wo + (size_t)(k0 + r) * 64 + cq * 16);
#pragma unroll
        for (int q = 0; q < 4; q++) *(float4*)&ws[r][cq * 16 + q * 4] = wsrc[q];
        __syncthreads();
        for (int k = 0; k < 64; k++) {
            float a = xs[r][k];
            const float* wr = &ws[k][cq * 16];
#pragma unroll
            for (int c = 0; c < 16; c++) acc[c] = fmaf(a, wr[c], acc[c]);
        }
        __syncthreads();
    }

    float p1 = 0.f, p2 = 0.f;
#pragma unroll
    for (int c = 0; c < 16; c++) {
        p1 = fmaf(acc[c], ao[cq * 16 + c], p1);
        p2 = fmaf(acc[c], ao[64 + cq * 16 + c], p2);
    }
    p1 += __shfl_xor(p1, 1); p1 += __shfl_xor(p1, 2);
    p2 += __shfl_xor(p2, 1); p2 += __shfl_xor(p2, 2);
    const int n = n0 + r;
    if (cq == 0) {
        F1b[(size_t)g * N_NODES + n] = p1 * LOG2E;
        F2b[(size_t)g * N_NODES + n] = p2 * LOG2E;
    }
    __hip_bfloat16* Hb = H2T + (size_t)g * FDIM * N_NODES;
#pragma unroll
    for (int c = 0; c < 16; c++)
        Hb[(size_t)(cq * 16 + c) * N_NODES + n] = __float2bfloat16(acc[c]);
}

extern "C" void kernel_launch(void* const* d_in, const int* in_sizes, int n_in,
                              void* d_out, int out_size, void* d_ws, size_t ws_size,
                              hipStream_t stream) {
    const float* x  = (const float*)d_in[0];
    const int* adj  = (const int*)d_in[1];
    const float* Wh = (const float*)d_in[2];
    const float* ah = (const float*)d_in[3];
    const float* Wo = (const float*)d_in[4];
    const float* ao = (const float*)d_in[5];

    char* ws = (char*)d_ws;
    __hip_bfloat16* Madd = (__hip_bfloat16*)(ws);                  // 2 MB
    float* F1  = (float*)(ws + 2097152);                           // 512 KB
    float* F2  = (float*)(ws + 2621440);                           // 512 KB
    float* F1b = (float*)(ws + 3145728);                           // 128 KB
    float* F2b = (float*)(ws + 3276800);                           // 128 KB
    __hip_bfloat16* H1T = (__hip_bfloat16*)(ws + 3407872);             // 16 MB
    __hip_bfloat16* HC  = (__hip_bfloat16*)(ws + 3407872 + 16777216);  // 16 MB
    __hip_bfloat16* H2T = (__hip_bfloat16*)(ws + 3407872 + 33554432);  //  4 MB
    float* out = (float*)d_out;

    k_maskf  <<<dim3(128),       dim3(256), 0, stream>>>(adj, Madd);
    k_proj1  <<<dim3(16, 32, 4), dim3(256), 0, stream>>>(x, Wh, ah, H1T, F1, F2);
    k_attn<1><<<dim3(32, 4, 8),  dim3(512), 0, stream>>>(H1T, F1, F2, Madd, HC, nullptr);
    k_proj2  <<<dim3(16, 32),    dim3(256), 0, stream>>>(HC, Wo, ao, H2T, F1b, F2b);
    k_attn<0><<<dim3(32, 1, 8),  dim3(512), 0, stream>>>(H2T, F1b, F2b, Madd, nullptr, out);
}

// Round 7
// 113.613 us; speedup vs baseline: 1.3418x; 1.1116x over previous
//
#include <hip/hip_runtime.h>
#include <hip/hip_bf16.h>

typedef short bf16x8 __attribute__((ext_vector_type(8)));
typedef float f32x4 __attribute__((ext_vector_type(4)));
typedef _Float16 half8 __attribute__((ext_vector_type(8)));
typedef _Float16 half4 __attribute__((ext_vector_type(4)));
typedef __fp16 cvt2_t __attribute__((ext_vector_type(2)));

#define N_NODES 1024
#define FDIM 64
#define NG 32   // B * Tp = 2 * 16
#define LOG2E 1.44269504088896f

// ---------------- K0: expand adjacency into additive bf16 mask ----------------
__global__ __launch_bounds__(256) void k_maskf(const int* __restrict__ adj,
                                               __hip_bfloat16* __restrict__ Madd) {
    int w = blockIdx.x * 256 + threadIdx.x;      // 32768 threads, 32 els each
    const int* p = adj + (size_t)w * 32;
    union { bf16x8 v[4]; __hip_bfloat16 hh[32]; } u;
#pragma unroll
    for (int b = 0; b < 32; b++)
        u.hh[b] = __float2bfloat16(p[b] > 0 ? 0.f : -2048.f);
    bf16x8* dst = (bf16x8*)(Madd + (size_t)w * 32);
#pragma unroll
    for (int q = 0; q < 4; q++) dst[q] = u.v[q];
}

// ---------------- K0b: transpose weights to fp16 ----------------
// wt1[h*64+o][k] = Wh[h][k][o]; wt2[o][k] = Wo[k][o]
__global__ __launch_bounds__(256) void k_prepw(const float* __restrict__ Wh,
                                               const float* __restrict__ Wo,
                                               _Float16* __restrict__ wt1,
                                               _Float16* __restrict__ wt2) {
    const int t = threadIdx.x;
    {   // wt1: row t of 256
        const int h = t >> 6, o = t & 63;
        const float* src = Wh + (size_t)h * 4096 + o;
#pragma unroll
        for (int k0 = 0; k0 < 64; k0 += 8) {
            union { half8 v; cvt2_t c[4]; } pk_;
#pragma unroll
            for (int kk = 0; kk < 8; kk += 2)
                pk_.c[kk >> 1] = __builtin_amdgcn_cvt_pkrtz(src[(k0 + kk) * 64],
                                                            src[(k0 + kk + 1) * 64]);
            *(half8*)(wt1 + (size_t)t * 64 + k0) = pk_.v;
        }
    }
    {   // wt2: row o, k-quarter kq
        const int kq = t >> 6, o = t & 63;
        const float* src = Wo + o;
#pragma unroll
        for (int k0 = kq * 64; k0 < kq * 64 + 64; k0 += 8) {
            union { half8 v; cvt2_t c[4]; } pk_;
#pragma unroll
            for (int kk = 0; kk < 8; kk += 2)
                pk_.c[kk >> 1] = __builtin_amdgcn_cvt_pkrtz(src[(k0 + kk) * 64],
                                                            src[(k0 + kk + 1) * 64]);
            *(half8*)(wt2 + (size_t)o * 256 + k0) = pk_.v;
        }
    }
}

// ---------------- K1: layer-1 projection via fp16 MFMA (4 heads fused) ----------------
// per block: 128 rows, all 4 heads x 64 f. 8 waves x 16 rows x 16 c-tiles.
__global__ __launch_bounds__(512, 2) void k_proj1(const float* __restrict__ x,
                                                  const _Float16* __restrict__ wt1,
                                                  const float* __restrict__ ah,
                                                  _Float16* __restrict__ H1T,
                                                  float* __restrict__ F1,
                                                  float* __restrict__ F2) {
    __shared__ _Float16 xs[128][64];   // XOR-swizzled 16B units
    const int t = threadIdx.x;
    const int nb = blockIdx.x, g = blockIdx.y;
    const int n0 = nb * 128;
    const int b = g >> 4, tstep = g & 15;

    {   // stage x tile: thread -> row r, quarter cq (16 f32 -> 2 units)
        const int r = t >> 2, cq = t & 3;
        const float* xr = x + (((size_t)(b * 17 + tstep) * N_NODES + n0 + r) * FDIM) + cq * 16;
        float4 v0 = *(const float4*)(xr);
        float4 v1 = *(const float4*)(xr + 4);
        float4 v2 = *(const float4*)(xr + 8);
        float4 v3 = *(const float4*)(xr + 12);
        union { half8 v; cvt2_t c[4]; } u0, u1;
        u0.c[0] = __builtin_amdgcn_cvt_pkrtz(v0.x, v0.y);
        u0.c[1] = __builtin_amdgcn_cvt_pkrtz(v0.z, v0.w);
        u0.c[2] = __builtin_amdgcn_cvt_pkrtz(v1.x, v1.y);
        u0.c[3] = __builtin_amdgcn_cvt_pkrtz(v1.z, v1.w);
        u1.c[0] = __builtin_amdgcn_cvt_pkrtz(v2.x, v2.y);
        u1.c[1] = __builtin_amdgcn_cvt_pkrtz(v2.z, v2.w);
        u1.c[2] = __builtin_amdgcn_cvt_pkrtz(v3.x, v3.y);
        u1.c[3] = __builtin_amdgcn_cvt_pkrtz(v3.z, v3.w);
        *(half8*)&xs[r][((2 * cq) ^ (r & 7)) * 8] = u0.v;
        *(half8*)&xs[r][((2 * cq + 1) ^ (r & 7)) * 8] = u1.v;
    }
    __syncthreads();

    const int wv = t >> 6, ln = t & 63, li = ln & 15, grp = ln >> 4;
    const int arow = wv * 16 + li;

    f32x4 acc[16];
#pragma unroll
    for (int q = 0; q < 16; q++) acc[q] = (f32x4){0.f, 0.f, 0.f, 0.f};

#pragma unroll
    for (int s = 0; s < 2; s++) {
        half8 af = *(const half8*)&xs[arow][((s * 4 + grp) ^ (arow & 7)) * 8];
#pragma unroll
        for (int tile = 0; tile < 16; tile++) {
            half8 bf = *(const half8*)(wt1 + (size_t)(tile * 16 + li) * 64 + s * 32 + grp * 8);
            acc[tile] = __builtin_amdgcn_mfma_f32_16x16x32_f16(af, bf, acc[tile], 0, 0, 0);
        }
    }

    // epilogue: H1T + score vectors
    const int nbase = n0 + wv * 16 + grp * 4;
#pragma unroll
    for (int h = 0; h < 4; h++) {
        float p1[4] = {0.f, 0.f, 0.f, 0.f}, p2[4] = {0.f, 0.f, 0.f, 0.f};
#pragma unroll
        for (int ot = 0; ot < 4; ot++) {
            float a1v = ah[h * 128 + ot * 16 + li];
            float a2v = ah[h * 128 + 64 + ot * 16 + li];
            f32x4 A = acc[h * 4 + ot];
#pragma unroll
            for (int r = 0; r < 4; r++) {
                p1[r] = fmaf(A[r], a1v, p1[r]);
                p2[r] = fmaf(A[r], a2v, p2[r]);
            }
        }
#pragma unroll
        for (int m = 1; m < 16; m <<= 1)
#pragma unroll
            for (int r = 0; r < 4; r++) {
                p1[r] += __shfl_xor(p1[r], m);
                p2[r] += __shfl_xor(p2[r], m);
            }
        if (li == 0) {
            const size_t gh = (size_t)h * NG + g;
#pragma unroll
            for (int r = 0; r < 4; r++) {
                F1[gh * N_NODES + nbase + r] = p1[r] * LOG2E;
                F2[gh * N_NODES + nbase + r] = p2[r] * LOG2E;
            }
        }
    }
#pragma unroll
    for (int tile = 0; tile < 16; tile++) {
        const int h = tile >> 2, ot = tile & 3;
        union { half4 v; cvt2_t c[2]; } st;
        st.c[0] = __builtin_amdgcn_cvt_pkrtz(acc[tile][0], acc[tile][1]);
        st.c[1] = __builtin_amdgcn_cvt_pkrtz(acc[tile][2], acc[tile][3]);
        _Float16* dst = H1T + (((size_t)h * NG + g) * FDIM + ot * 16 + li) * N_NODES + nbase;
        *(half4*)dst = st.v;
    }
}

// ---------------- fused masked attention (fp16 pipeline) ----------------
template<int CONCAT>
__global__ __launch_bounds__(512, 4) void k_attn(
    const _Float16* __restrict__ HT,         // [G][64 f][1024 n] f16
    const float* __restrict__ F1,            // [G][1024] (×log2e)
    const float* __restrict__ F2,
    const __hip_bfloat16* __restrict__ Madd, // [1024][1024] additive mask (bf16)
    _Float16* __restrict__ HC,               // concat out (CONCAT=1)
    float* __restrict__ out)                 // final out (CONCAT=0)
{
    __shared__ _Float16 vt[64][256];   // linear rows; unit-XOR swizzle
    __shared__ float f2s[N_NODES];
    const int t = threadIdx.x;
    const int g = blockIdx.x, h = blockIdx.y, nb = blockIdx.z;
    const int i0 = nb * 128;
    const size_t gidx = CONCAT ? ((size_t)h * NG + g) : (size_t)g;

    ((float2*)f2s)[t] = ((const float2*)(F2 + gidx * N_NODES))[t];

    const int wv = t >> 6, ln = t & 63;
    const int li = ln & 15, grp = ln >> 4, jb = grp * 8;
    const int lx = li & 7;
    const int il = wv * 16 + li;
    const float f1v = F1[gidx * N_NODES + i0 + il];

    const _Float16* Hg = HT + gidx * (size_t)(FDIM * N_NODES);
    const int srow = wv * 8 + (ln >> 3);          // staging row (f)
    const int swu = (ln & 7) ^ (srow & 7);        // swizzled low-3 unit
    const _Float16* srcb = Hg + (size_t)srow * N_NODES + (ln & 7) * 8;
    const __hip_bfloat16* Mp = Madd + (size_t)(i0 + il) * N_NODES + jb;

    f32x4 acc[4], acc5;
#pragma unroll
    for (int q = 0; q < 4; q++) acc[q] = (f32x4){0.f, 0.f, 0.f, 0.f};
    acc5 = (f32x4){0.f, 0.f, 0.f, 0.f};

    union { half8 v; unsigned short s[8]; } onesu;
#pragma unroll
    for (int q = 0; q < 8; q++) onesu.s[q] = 0x3C00;   // fp16 1.0
    const half8 ones = onesu.v;

    half8 stg[4];
#pragma unroll
    for (int k2 = 0; k2 < 4; k2++) stg[k2] = *(const half8*)(srcb + k2 * 64);
    bf16x8 m0 = *(const bf16x8*)Mp;               // 2-deep mask prefetch
    bf16x8 m1 = *(const bf16x8*)(Mp + 32);

    for (int jt = 0; jt < 4; jt++) {
        __syncthreads();                      // all waves done reading vt
#pragma unroll
        for (int k2 = 0; k2 < 4; k2++)
            *(half8*)&vt[srow][(k2 * 8 + swu) * 8] = stg[k2];
        if (jt < 3) {                         // issue next tile's global loads
#pragma unroll
            for (int k2 = 0; k2 < 4; k2++)
                stg[k2] = *(const half8*)(srcb + (jt + 1) * 256 + k2 * 64);
        }
        __syncthreads();                      // vt fully written

#pragma unroll
        for (int jc = 0; jc < 8; jc++) {
            union { bf16x8 v; unsigned u[4]; } mc;
            mc.v = m0;
            m0 = m1;
            if (!(jt == 3 && jc >= 6))        // rotate 2-deep prefetch
                m1 = *(const bf16x8*)(Mp + 64);
            Mp += 32;

            const float* f2p = &f2s[jt * 256 + jc * 32 + jb];
            float4 fa = *(const float4*)f2p;
            float4 fb = *(const float4*)(f2p + 4);
            union { half8 v; cvt2_t c[4]; } afr;
            {
                float mlo, mhi, s0, s1;
                mlo = __uint_as_float(mc.u[0] << 16);
                mhi = __uint_as_float(mc.u[0] & 0xffff0000u);
                s0 = f1v + fa.x + mlo; s1 = f1v + fa.y + mhi;
                s0 = fmaxf(s0, 0.2f * s0); s1 = fmaxf(s1, 0.2f * s1);
                afr.c[0] = __builtin_amdgcn_cvt_pkrtz(__builtin_amdgcn_exp2f(s0),
                                                      __builtin_amdgcn_exp2f(s1));
                mlo = __uint_as_float(mc.u[1] << 16);
                mhi = __uint_as_float(mc.u[1] & 0xffff0000u);
                s0 = f1v + fa.z + mlo; s1 = f1v + fa.w + mhi;
                s0 = fmaxf(s0, 0.2f * s0); s1 = fmaxf(s1, 0.2f * s1);
                afr.c[1] = __builtin_amdgcn_cvt_pkrtz(__builtin_amdgcn_exp2f(s0),
                                                      __builtin_amdgcn_exp2f(s1));
                mlo = __uint_as_float(mc.u[2] << 16);
                mhi = __uint_as_float(mc.u[2] & 0xffff0000u);
                s0 = f1v + fb.x + mlo; s1 = f1v + fb.y + mhi;
                s0 = fmaxf(s0, 0.2f * s0); s1 = fmaxf(s1, 0.2f * s1);
                afr.c[2] = __builtin_amdgcn_cvt_pkrtz(__builtin_amdgcn_exp2f(s0),
                                                      __builtin_amdgcn_exp2f(s1));
                mlo = __uint_as_float(mc.u[3] << 16);
                mhi = __uint_as_float(mc.u[3] & 0xffff0000u);
                s0 = f1v + fb.z + mlo; s1 = f1v + fb.w + mhi;
                s0 = fmaxf(s0, 0.2f * s0); s1 = fmaxf(s1, 0.2f * s1);
                afr.c[3] = __builtin_amdgcn_cvt_pkrtz(__builtin_amdgcn_exp2f(s0),
                                                      __builtin_amdgcn_exp2f(s1));
            }
            // swizzled B-frag read: unit = jc*4+grp, low3 XOR li&7
            const int ub = (jc >> 1) * 8 + (((jc & 1) * 4 + grp) ^ lx);
#pragma unroll
            for (int q = 0; q < 4; q++) {
                half8 bfr = *(const half8*)&vt[q * 16 + li][ub * 8];
                acc[q] = __builtin_amdgcn_mfma_f32_16x16x32_f16(afr.v, bfr, acc[q], 0, 0, 0);
            }
            acc5 = __builtin_amdgcn_mfma_f32_16x16x32_f16(afr.v, ones, acc5, 0, 0, 0);
        }
    }

    float rin[4];
#pragma unroll
    for (int r2 = 0; r2 < 4; r2++) rin[r2] = 1.0f / acc5[r2];

    if (CONCAT) {
        _Float16* HCg = HC + (size_t)g * N_NODES * 256 + h * 64;
#pragma unroll
        for (int q = 0; q < 4; q++)
#pragma unroll
            for (int r2 = 0; r2 < 4; r2++) {
                int irow = wv * 16 + grp * 4 + r2;
                float v = acc[q][r2] * rin[r2];
                v = v > 0.f ? v : expm1f(v); // ELU
                HCg[(size_t)(i0 + irow) * 256 + q * 16 + li] = (_Float16)v;
            }
    } else {
        float* og = out + (size_t)g * N_NODES * FDIM;
#pragma unroll
        for (int q = 0; q < 4; q++)
#pragma unroll
            for (int r2 = 0; r2 < 4; r2++) {
                int irow = wv * 16 + grp * 4 + r2;
                float v = acc[q][r2] * rin[r2];
                og[(size_t)(i0 + irow) * FDIM + q * 16 + li] = v > 0.f ? v : 0.f;
            }
    }
}

// ---------------- K3: layer-2 projection via fp16 MFMA ----------------
// per block: 128 rows x 64 out, K=256. 8 waves x 16 rows x 4 c-tiles.
__global__ __launch_bounds__(512, 2) void k_proj2(const _Float16* __restrict__ HC,
                                                  const _Float16* __restrict__ wt2,
                                                  const float* __restrict__ ao,
                                                  _Float16* __restrict__ H2T,
                                                  float* __restrict__ F1b,
                                                  float* __restrict__ F2b) {
    __shared__ _Float16 xs[128][256];  // 64KB, XOR-swizzled within 8-unit groups
    const int t = threadIdx.x;
    const int nb = blockIdx.x, g = blockIdx.y;
    const int n0 = nb * 128;

    {   // stage HC tile: thread -> row r, quarter cq (64 f16 = 8 units)
        const int r = t >> 2, cq = t & 3;
        const _Float16* src = HC + ((size_t)g * N_NODES + n0 + r) * 256 + cq * 64;
#pragma unroll
        for (int uu = 0; uu < 8; uu++) {
            int u = cq * 8 + uu;
            half8 v = *(const half8*)(src + uu * 8);
            int us = (u & 24) | ((u ^ r) & 7);
            *(half8*)&xs[r][us * 8] = v;
        }
    }
    __syncthreads();

    const int wv = t >> 6, ln = t & 63, li = ln & 15, grp = ln >> 4;
    const int arow = wv * 16 + li;

    f32x4 acc[4];
#pragma unroll
    for (int q = 0; q < 4; q++) acc[q] = (f32x4){0.f, 0.f, 0.f, 0.f};

#pragma unroll
    for (int s = 0; s < 8; s++) {
        int u = s * 4 + grp;
        int us = (u & 24) | ((u ^ arow) & 7);
        half8 af = *(const half8*)&xs[arow][us * 8];
#pragma unroll
        for (int tile = 0; tile < 4; tile++) {
            half8 bf = *(const half8*)(wt2 + (size_t)(tile * 16 + li) * 256 + s * 32 + grp * 8);
            acc[tile] = __builtin_amdgcn_mfma_f32_16x16x32_f16(af, bf, acc[tile], 0, 0, 0);
        }
    }

    const int nbase = n0 + wv * 16 + grp * 4;
    {
        float p1[4] = {0.f, 0.f, 0.f, 0.f}, p2[4] = {0.f, 0.f, 0.f, 0.f};
#pragma unroll
        for (int ot = 0; ot < 4; ot++) {
            float a1v = ao[ot * 16 + li];
            float a2v = ao[64 + ot * 16 + li];
            f32x4 A = acc[ot];
#pragma unroll
            for (int r = 0; r < 4; r++) {
                p1[r] = fmaf(A[r], a1v, p1[r]);
                p2[r] = fmaf(A[r], a2v, p2[r]);
            }
        }
#pragma unroll
        for (int m = 1; m < 16; m <<= 1)
#pragma unroll
            for (int r = 0; r < 4; r++) {
                p1[r] += __shfl_xor(p1[r], m);
                p2[r] += __shfl_xor(p2[r], m);
            }
        if (li == 0) {
#pragma unroll
            for (int r = 0; r < 4; r++) {
                F1b[(size_t)g * N_NODES + nbase + r] = p1[r] * LOG2E;
                F2b[(size_t)g * N_NODES + nbase + r] = p2[r] * LOG2E;
            }
        }
    }
#pragma unroll
    for (int tile = 0; tile < 4; tile++) {
        union { half4 v; cvt2_t c[2]; } st;
        st.c[0] = __builtin_amdgcn_cvt_pkrtz(acc[tile][0], acc[tile][1]);
        st.c[1] = __builtin_amdgcn_cvt_pkrtz(acc[tile][2], acc[tile][3]);
        _Float16* dst = H2T + ((size_t)g * FDIM + tile * 16 + li) * N_NODES + nbase;
        *(half4*)dst = st.v;
    }
}

extern "C" void kernel_launch(void* const* d_in, const int* in_sizes, int n_in,
                              void* d_out, int out_size, void* d_ws, size_t ws_size,
                              hipStream_t stream) {
    const float* x  = (const float*)d_in[0];
    const int* adj  = (const int*)d_in[1];
    const float* Wh = (const float*)d_in[2];
    const float* ah = (const float*)d_in[3];
    const float* Wo = (const float*)d_in[4];
    const float* ao = (const float*)d_in[5];

    char* ws = (char*)d_ws;
    __hip_bfloat16* Madd = (__hip_bfloat16*)(ws);            // 2 MB
    _Float16* wt1 = (_Float16*)(ws + 2097152);               // 32 KB
    _Float16* wt2 = (_Float16*)(ws + 2129920);               // 32 KB
    float* F1  = (float*)(ws + 2162688);                     // 512 KB
    float* F2  = (float*)(ws + 2686976);                     // 512 KB
    float* F1b = (float*)(ws + 3211264);                     // 128 KB
    float* F2b = (float*)(ws + 3342336);                     // 128 KB
    _Float16* H1T = (_Float16*)(ws + 3473408);               // 16 MB
    _Float16* HC  = (_Float16*)(ws + 3473408 + 16777216);    // 16 MB
    _Float16* H2T = (_Float16*)(ws + 3473408 + 33554432);    //  4 MB
    float* out = (float*)d_out;

    k_maskf  <<<dim3(128),       dim3(256), 0, stream>>>(adj, Madd);
    k_prepw  <<<dim3(1),         dim3(256), 0, stream>>>(Wh, Wo, wt1, wt2);
    k_proj1  <<<dim3(8, 32),     dim3(512), 0, stream>>>(x, wt1, ah, H1T, F1, F2);
    k_attn<1><<<dim3(32, 4, 8),  dim3(512), 0, stream>>>(H1T, F1, F2, Madd, HC, nullptr);
    k_proj2  <<<dim3(8, 32),     dim3(512), 0, stream>>>(HC, wt2, ao, H2T, F1b, F2b);
    k_attn<0><<<dim3(32, 1, 8),  dim3(512), 0, stream>>>(H2T, F1b, F2b, Madd, nullptr, out);
}

// Round 8
// 111.324 us; speedup vs baseline: 1.3694x; 1.0206x over previous
//
#include <hip/hip_runtime.h>
#include <hip/hip_bf16.h>

typedef short bf16x8 __attribute__((ext_vector_type(8)));
typedef float f32x4 __attribute__((ext_vector_type(4)));
typedef _Float16 half8 __attribute__((ext_vector_type(8)));
typedef _Float16 half4 __attribute__((ext_vector_type(4)));
typedef __fp16 cvt2_t __attribute__((ext_vector_type(2)));

#define N_NODES 1024
#define FDIM 64
#define NG 32   // B * Tp = 2 * 16
#define LOG2E 1.44269504088896f

// ---------------- K0: fused prep — additive mask + weight transpose ----------------
// blocks 0..127: Madd[i][j] = adj ? 0 : -2048 (bf16)
// blocks 128..131: wt1[h*64+o][k] = Wh[h][k][o] (fp16)
// blocks 132..135: wt2[o][k] = Wo[k][o] (fp16)
__global__ __launch_bounds__(256) void k_prep(const int* __restrict__ adj,
                                              const float* __restrict__ Wh,
                                              const float* __restrict__ Wo,
                                              __hip_bfloat16* __restrict__ Madd,
                                              _Float16* __restrict__ wt1,
                                              _Float16* __restrict__ wt2) {
    const int bb = blockIdx.x, t = threadIdx.x;
    if (bb < 128) {
        int w = bb * 256 + t;
        const int* p = adj + (size_t)w * 32;
        union { bf16x8 v[4]; __hip_bfloat16 hh[32]; } u;
#pragma unroll
        for (int b = 0; b < 32; b++)
            u.hh[b] = __float2bfloat16(p[b] > 0 ? 0.f : -2048.f);
        bf16x8* dst = (bf16x8*)(Madd + (size_t)w * 32);
#pragma unroll
        for (int q = 0; q < 4; q++) dst[q] = u.v[q];
    } else if (bb < 132) {
        const int row = (bb - 128) * 64 + (t >> 2);   // 0..255 = h*64+o
        const int kq = t & 3;
        const float* src = Wh + (size_t)(row >> 6) * 4096 + (row & 63);
#pragma unroll
        for (int kk = 0; kk < 16; kk += 8) {
            const int k0 = kq * 16 + kk;
            union { half8 v; cvt2_t c[4]; } pk_;
#pragma unroll
            for (int j = 0; j < 8; j += 2)
                pk_.c[j >> 1] = __builtin_amdgcn_cvt_pkrtz(src[(k0 + j) * 64],
                                                           src[(k0 + j + 1) * 64]);
            *(half8*)(wt1 + (size_t)row * 64 + k0) = pk_.v;
        }
    } else {
        const int o = (bb - 132) * 16 + (t >> 4);     // 0..63
        const int k0 = (t & 15) * 16;
        const float* src = Wo + o;
#pragma unroll
        for (int kk = 0; kk < 16; kk += 8) {
            union { half8 v; cvt2_t c[4]; } pk_;
#pragma unroll
            for (int j = 0; j < 8; j += 2)
                pk_.c[j >> 1] = __builtin_amdgcn_cvt_pkrtz(src[(k0 + kk + j) * 64],
                                                           src[(k0 + kk + j + 1) * 64]);
            *(half8*)(wt2 + (size_t)o * 256 + k0 + kk) = pk_.v;
        }
    }
}

// ---------------- K1: layer-1 projection via fp16 MFMA (4 heads fused) ----------------
__global__ __launch_bounds__(512, 2) void k_proj1(const float* __restrict__ x,
                                                  const _Float16* __restrict__ wt1,
                                                  const float* __restrict__ ah,
                                                  _Float16* __restrict__ H1T,
                                                  float* __restrict__ F1,
                                                  float* __restrict__ F2) {
    __shared__ _Float16 xs[128][64];   // XOR-swizzled 16B units
    const int t = threadIdx.x;
    const int nb = blockIdx.x, g = blockIdx.y;
    const int n0 = nb * 128;
    const int b = g >> 4, tstep = g & 15;

    {   // stage x tile
        const int r = t >> 2, cq = t & 3;
        const float* xr = x + (((size_t)(b * 17 + tstep) * N_NODES + n0 + r) * FDIM) + cq * 16;
        float4 v0 = *(const float4*)(xr);
        float4 v1 = *(const float4*)(xr + 4);
        float4 v2 = *(const float4*)(xr + 8);
        float4 v3 = *(const float4*)(xr + 12);
        union { half8 v; cvt2_t c[4]; } u0, u1;
        u0.c[0] = __builtin_amdgcn_cvt_pkrtz(v0.x, v0.y);
        u0.c[1] = __builtin_amdgcn_cvt_pkrtz(v0.z, v0.w);
        u0.c[2] = __builtin_amdgcn_cvt_pkrtz(v1.x, v1.y);
        u0.c[3] = __builtin_amdgcn_cvt_pkrtz(v1.z, v1.w);
        u1.c[0] = __builtin_amdgcn_cvt_pkrtz(v2.x, v2.y);
        u1.c[1] = __builtin_amdgcn_cvt_pkrtz(v2.z, v2.w);
        u1.c[2] = __builtin_amdgcn_cvt_pkrtz(v3.x, v3.y);
        u1.c[3] = __builtin_amdgcn_cvt_pkrtz(v3.z, v3.w);
        *(half8*)&xs[r][((2 * cq) ^ (r & 7)) * 8] = u0.v;
        *(half8*)&xs[r][((2 * cq + 1) ^ (r & 7)) * 8] = u1.v;
    }
    __syncthreads();

    const int wv = t >> 6, ln = t & 63, li = ln & 15, grp = ln >> 4;
    const int arow = wv * 16 + li;

    f32x4 acc[16];
#pragma unroll
    for (int q = 0; q < 16; q++) acc[q] = (f32x4){0.f, 0.f, 0.f, 0.f};

#pragma unroll
    for (int s = 0; s < 2; s++) {
        half8 af = *(const half8*)&xs[arow][((s * 4 + grp) ^ (arow & 7)) * 8];
#pragma unroll
        for (int tile = 0; tile < 16; tile++) {
            half8 bf = *(const half8*)(wt1 + (size_t)(tile * 16 + li) * 64 + s * 32 + grp * 8);
            acc[tile] = __builtin_amdgcn_mfma_f32_16x16x32_f16(af, bf, acc[tile], 0, 0, 0);
        }
    }

    const int nbase = n0 + wv * 16 + grp * 4;
#pragma unroll
    for (int h = 0; h < 4; h++) {
        float p1[4] = {0.f, 0.f, 0.f, 0.f}, p2[4] = {0.f, 0.f, 0.f, 0.f};
#pragma unroll
        for (int ot = 0; ot < 4; ot++) {
            float a1v = ah[h * 128 + ot * 16 + li];
            float a2v = ah[h * 128 + 64 + ot * 16 + li];
            f32x4 A = acc[h * 4 + ot];
#pragma unroll
            for (int r = 0; r < 4; r++) {
                p1[r] = fmaf(A[r], a1v, p1[r]);
                p2[r] = fmaf(A[r], a2v, p2[r]);
            }
        }
#pragma unroll
        for (int m = 1; m < 16; m <<= 1)
#pragma unroll
            for (int r = 0; r < 4; r++) {
                p1[r] += __shfl_xor(p1[r], m);
                p2[r] += __shfl_xor(p2[r], m);
            }
        if (li == 0) {
            const size_t gh = (size_t)h * NG + g;
#pragma unroll
            for (int r = 0; r < 4; r++) {
                F1[gh * N_NODES + nbase + r] = p1[r] * LOG2E;
                F2[gh * N_NODES + nbase + r] = p2[r] * LOG2E;
            }
        }
    }
#pragma unroll
    for (int tile = 0; tile < 16; tile++) {
        const int h = tile >> 2, ot = tile & 3;
        union { half4 v; cvt2_t c[2]; } st;
        st.c[0] = __builtin_amdgcn_cvt_pkrtz(acc[tile][0], acc[tile][1]);
        st.c[1] = __builtin_amdgcn_cvt_pkrtz(acc[tile][2], acc[tile][3]);
        _Float16* dst = H1T + (((size_t)h * NG + g) * FDIM + ot * 16 + li) * N_NODES + nbase;
        *(half4*)dst = st.v;
    }
}

// ---------------- fused masked attention (fp16, single-barrier pipeline) ----------------
// 128 rows/block, 8 waves; j-tile 256 DOUBLE-buffered in LDS (XOR-swizzled);
// per jt: write next buf (reg-prefetched), issue jt+2 loads, 8-jc compute, 1 barrier.
template<int CONCAT>
__global__ __launch_bounds__(512, 4) void k_attn(
    const _Float16* __restrict__ HT,         // [G][64 f][1024 n] f16
    const float* __restrict__ F1,            // [G][1024] (×log2e)
    const float* __restrict__ F2,
    const __hip_bfloat16* __restrict__ Madd, // [1024][1024] additive mask (bf16)
    _Float16* __restrict__ HC,               // concat out (CONCAT=1)
    float* __restrict__ out)                 // final out (CONCAT=0)
{
    __shared__ _Float16 vt[2][64][256];      // 64KB double buffer
    __shared__ float f2s[N_NODES];
    const int t = threadIdx.x;
    const int g = blockIdx.x, h = blockIdx.y, nb = blockIdx.z;
    const int i0 = nb * 128;
    const size_t gidx = CONCAT ? ((size_t)h * NG + g) : (size_t)g;

    ((float2*)f2s)[t] = ((const float2*)(F2 + gidx * N_NODES))[t];

    const int wv = t >> 6, ln = t & 63;
    const int li = ln & 15, grp = ln >> 4, jb = grp * 8;
    const int lx = li & 7;
    const int il = wv * 16 + li;
    const float f1v = F1[gidx * N_NODES + i0 + il];

    const _Float16* Hg = HT + gidx * (size_t)(FDIM * N_NODES);
    const int srow = wv * 8 + (ln >> 3);          // staging row (f)
    const int swu = (ln & 7) ^ (srow & 7);        // swizzled low-3 unit
    const _Float16* srcb = Hg + (size_t)srow * N_NODES + (ln & 7) * 8;
    const __hip_bfloat16* Mp = Madd + (size_t)(i0 + il) * N_NODES + jb;

    f32x4 acc[4], acc5;
#pragma unroll
    for (int q = 0; q < 4; q++) acc[q] = (f32x4){0.f, 0.f, 0.f, 0.f};
    acc5 = (f32x4){0.f, 0.f, 0.f, 0.f};

    union { half8 v; unsigned short s[8]; } onesu;
#pragma unroll
    for (int q = 0; q < 8; q++) onesu.s[q] = 0x3C00;   // fp16 1.0
    const half8 ones = onesu.v;

    half8 stg[4];
    // prologue: buf0 <- jt0; stg <- jt1
#pragma unroll
    for (int k2 = 0; k2 < 4; k2++) stg[k2] = *(const half8*)(srcb + k2 * 64);
#pragma unroll
    for (int k2 = 0; k2 < 4; k2++)
        *(half8*)&vt[0][srow][(k2 * 8 + swu) * 8] = stg[k2];
#pragma unroll
    for (int k2 = 0; k2 < 4; k2++) stg[k2] = *(const half8*)(srcb + 256 + k2 * 64);
    bf16x8 m0 = *(const bf16x8*)Mp;               // 2-deep mask prefetch
    bf16x8 m1 = *(const bf16x8*)(Mp + 32);
    __syncthreads();                               // buf0 + f2s ready

    for (int jt = 0; jt < 4; jt++) {
        if (jt < 3) {                              // write next buf (overlaps compute)
#pragma unroll
            for (int k2 = 0; k2 < 4; k2++)
                *(half8*)&vt[(jt + 1) & 1][srow][(k2 * 8 + swu) * 8] = stg[k2];
        }
        if (jt < 2) {                              // issue jt+2 global loads
#pragma unroll
            for (int k2 = 0; k2 < 4; k2++)
                stg[k2] = *(const half8*)(srcb + (jt + 2) * 256 + k2 * 64);
        }

#pragma unroll
        for (int jc = 0; jc < 8; jc++) {
            union { bf16x8 v; unsigned u[4]; } mc;
            mc.v = m0;
            m0 = m1;
            if (!(jt == 3 && jc >= 6))
                m1 = *(const bf16x8*)(Mp + 64);
            Mp += 32;

            const float* f2p = &f2s[jt * 256 + jc * 32 + jb];
            float4 fa = *(const float4*)f2p;
            float4 fb = *(const float4*)(f2p + 4);
            union { half8 v; cvt2_t c[4]; } afr;
            {
                float mlo, mhi, s0, s1;
                mlo = __uint_as_float(mc.u[0] << 16);
                mhi = __uint_as_float(mc.u[0] & 0xffff0000u);
                s0 = f1v + fa.x + mlo; s1 = f1v + fa.y + mhi;
                s0 = fmaxf(s0, 0.2f * s0); s1 = fmaxf(s1, 0.2f * s1);
                afr.c[0] = __builtin_amdgcn_cvt_pkrtz(__builtin_amdgcn_exp2f(s0),
                                                      __builtin_amdgcn_exp2f(s1));
                mlo = __uint_as_float(mc.u[1] << 16);
                mhi = __uint_as_float(mc.u[1] & 0xffff0000u);
                s0 = f1v + fa.z + mlo; s1 = f1v + fa.w + mhi;
                s0 = fmaxf(s0, 0.2f * s0); s1 = fmaxf(s1, 0.2f * s1);
                afr.c[1] = __builtin_amdgcn_cvt_pkrtz(__builtin_amdgcn_exp2f(s0),
                                                      __builtin_amdgcn_exp2f(s1));
                mlo = __uint_as_float(mc.u[2] << 16);
                mhi = __uint_as_float(mc.u[2] & 0xffff0000u);
                s0 = f1v + fb.x + mlo; s1 = f1v + fb.y + mhi;
                s0 = fmaxf(s0, 0.2f * s0); s1 = fmaxf(s1, 0.2f * s1);
                afr.c[2] = __builtin_amdgcn_cvt_pkrtz(__builtin_amdgcn_exp2f(s0),
                                                      __builtin_amdgcn_exp2f(s1));
                mlo = __uint_as_float(mc.u[3] << 16);
                mhi = __uint_as_float(mc.u[3] & 0xffff0000u);
                s0 = f1v + fb.z + mlo; s1 = f1v + fb.w + mhi;
                s0 = fmaxf(s0, 0.2f * s0); s1 = fmaxf(s1, 0.2f * s1);
                afr.c[3] = __builtin_amdgcn_cvt_pkrtz(__builtin_amdgcn_exp2f(s0),
                                                      __builtin_amdgcn_exp2f(s1));
            }
            const int ub = (jc >> 1) * 8 + (((jc & 1) * 4 + grp) ^ lx);
#pragma unroll
            for (int q = 0; q < 4; q++) {
                half8 bfr = *(const half8*)&vt[jt & 1][q * 16 + li][ub * 8];
                acc[q] = __builtin_amdgcn_mfma_f32_16x16x32_f16(afr.v, bfr, acc[q], 0, 0, 0);
            }
            acc5 = __builtin_amdgcn_mfma_f32_16x16x32_f16(afr.v, ones, acc5, 0, 0, 0);
        }
        if (jt < 3) __syncthreads();               // single barrier per jt
    }

    float rin[4];
#pragma unroll
    for (int r2 = 0; r2 < 4; r2++) rin[r2] = 1.0f / acc5[r2];

    if (CONCAT) {
        _Float16* HCg = HC + (size_t)g * N_NODES * 256 + h * 64;
#pragma unroll
        for (int q = 0; q < 4; q++)
#pragma unroll
            for (int r2 = 0; r2 < 4; r2++) {
                int irow = wv * 16 + grp * 4 + r2;
                float v = acc[q][r2] * rin[r2];
                v = v > 0.f ? v : expm1f(v); // ELU
                HCg[(size_t)(i0 + irow) * 256 + q * 16 + li] = (_Float16)v;
            }
    } else {
        float* og = out + (size_t)g * N_NODES * FDIM;
#pragma unroll
        for (int q = 0; q < 4; q++)
#pragma unroll
            for (int r2 = 0; r2 < 4; r2++) {
                int irow = wv * 16 + grp * 4 + r2;
                float v = acc[q][r2] * rin[r2];
                og[(size_t)(i0 + irow) * FDIM + q * 16 + li] = v > 0.f ? v : 0.f;
            }
    }
}

// ---------------- K3: layer-2 projection via fp16 MFMA ----------------
__global__ __launch_bounds__(512, 2) void k_proj2(const _Float16* __restrict__ HC,
                                                  const _Float16* __restrict__ wt2,
                                                  const float* __restrict__ ao,
                                                  _Float16* __restrict__ H2T,
                                                  float* __restrict__ F1b,
                                                  float* __restrict__ F2b) {
    __shared__ _Float16 xs[128][256];  // 64KB, XOR-swizzled within 8-unit groups
    const int t = threadIdx.x;
    const int nb = blockIdx.x, g = blockIdx.y;
    const int n0 = nb * 128;

    {   // stage HC tile
        const int r = t >> 2, cq = t & 3;
        const _Float16* src = HC + ((size_t)g * N_NODES + n0 + r) * 256 + cq * 64;
#pragma unroll
        for (int uu = 0; uu < 8; uu++) {
            int u = cq * 8 + uu;
            half8 v = *(const half8*)(src + uu * 8);
            int us = (u & 24) | ((u ^ r) & 7);
            *(half8*)&xs[r][us * 8] = v;
        }
    }
    __syncthreads();

    const int wv = t >> 6, ln = t & 63, li = ln & 15, grp = ln >> 4;
    const int arow = wv * 16 + li;

    f32x4 acc[4];
#pragma unroll
    for (int q = 0; q < 4; q++) acc[q] = (f32x4){0.f, 0.f, 0.f, 0.f};

#pragma unroll
    for (int s = 0; s < 8; s++) {
        int u = s * 4 + grp;
        int us = (u & 24) | ((u ^ arow) & 7);
        half8 af = *(const half8*)&xs[arow][us * 8];
#pragma unroll
        for (int tile = 0; tile < 4; tile++) {
            half8 bf = *(const half8*)(wt2 + (size_t)(tile * 16 + li) * 256 + s * 32 + grp * 8);
            acc[tile] = __builtin_amdgcn_mfma_f32_16x16x32_f16(af, bf, acc[tile], 0, 0, 0);
        }
    }

    const int nbase = n0 + wv * 16 + grp * 4;
    {
        float p1[4] = {0.f, 0.f, 0.f, 0.f}, p2[4] = {0.f, 0.f, 0.f, 0.f};
#pragma unroll
        for (int ot = 0; ot < 4; ot++) {
            float a1v = ao[ot * 16 + li];
            float a2v = ao[64 + ot * 16 + li];
            f32x4 A = acc[ot];
#pragma unroll
            for (int r = 0; r < 4; r++) {
                p1[r] = fmaf(A[r], a1v, p1[r]);
                p2[r] = fmaf(A[r], a2v, p2[r]);
            }
        }
#pragma unroll
        for (int m = 1; m < 16; m <<= 1)
#pragma unroll
            for (int r = 0; r < 4; r++) {
                p1[r] += __shfl_xor(p1[r], m);
                p2[r] += __shfl_xor(p2[r], m);
            }
        if (li == 0) {
#pragma unroll
            for (int r = 0; r < 4; r++) {
                F1b[(size_t)g * N_NODES + nbase + r] = p1[r] * LOG2E;
                F2b[(size_t)g * N_NODES + nbase + r] = p2[r] * LOG2E;
            }
        }
    }
#pragma unroll
    for (int tile = 0; tile < 4; tile++) {
        union { half4 v; cvt2_t c[2]; } st;
        st.c[0] = __builtin_amdgcn_cvt_pkrtz(acc[tile][0], acc[tile][1]);
        st.c[1] = __builtin_amdgcn_cvt_pkrtz(acc[tile][2], acc[tile][3]);
        _Float16* dst = H2T + ((size_t)g * FDIM + tile * 16 + li) * N_NODES + nbase;
        *(half4*)dst = st.v;
    }
}

extern "C" void kernel_launch(void* const* d_in, const int* in_sizes, int n_in,
                              void* d_out, int out_size, void* d_ws, size_t ws_size,
                              hipStream_t stream) {
    const float* x  = (const float*)d_in[0];
    const int* adj  = (const int*)d_in[1];
    const float* Wh = (const float*)d_in[2];
    const float* ah = (const float*)d_in[3];
    const float* Wo = (const float*)d_in[4];
    const float* ao = (const float*)d_in[5];

    char* ws = (char*)d_ws;
    __hip_bfloat16* Madd = (__hip_bfloat16*)(ws);            // 2 MB
    _Float16* wt1 = (_Float16*)(ws + 2097152);               // 32 KB
    _Float16* wt2 = (_Float16*)(ws + 2129920);               // 32 KB
    float* F1  = (float*)(ws + 2162688);                     // 512 KB
    float* F2  = (float*)(ws + 2686976);                     // 512 KB
    float* F1b = (float*)(ws + 3211264);                     // 128 KB
    float* F2b = (float*)(ws + 3342336);                     // 128 KB
    _Float16* H1T = (_Float16*)(ws + 3473408);               // 16 MB
    _Float16* HC  = (_Float16*)(ws + 3473408 + 16777216);    // 16 MB
    _Float16* H2T = (_Float16*)(ws + 3473408 + 33554432);    //  4 MB
    float* out = (float*)d_out;

    k_prep   <<<dim3(136),       dim3(256), 0, stream>>>(adj, Wh, Wo, Madd, wt1, wt2);
    k_proj1  <<<dim3(8, 32),     dim3(512), 0, stream>>>(x, wt1, ah, H1T, F1, F2);
    k_attn<1><<<dim3(32, 4, 8),  dim3(512), 0, stream>>>(H1T, F1, F2, Madd, HC, nullptr);
    k_proj2  <<<dim3(8, 32),     dim3(512), 0, stream>>>(HC, wt2, ao, H2T, F1b, F2b);
    k_attn<0><<<dim3(32, 1, 8),  dim3(512), 0, stream>>>(H2T, F1b, F2b, Madd, nullptr, out);
}

// Round 9
// 109.210 us; speedup vs baseline: 1.3959x; 1.0194x over previous
//
#include <hip/hip_runtime.h>
#include <hip/hip_bf16.h>

typedef short bf16x8 __attribute__((ext_vector_type(8)));
typedef float f32x4 __attribute__((ext_vector_type(4)));
typedef _Float16 half8 __attribute__((ext_vector_type(8)));
typedef _Float16 half4 __attribute__((ext_vector_type(4)));
typedef __fp16 cvt2_t __attribute__((ext_vector_type(2)));

#define N_NODES 1024
#define FDIM 64
#define NG 32   // B * Tp = 2 * 16
#define LOG2E 1.44269504088896f

// ---------------- K0: fused prep — byte mask + weight transpose ----------------
// blocks 0..127: Mbyte[i][j] = adj ? 1 : 0 (uchar)
// blocks 128..131: wt1[h*64+o][k] = Wh[h][k][o] (fp16)
// blocks 132..135: wt2[o][k] = Wo[k][o] (fp16)
__global__ __launch_bounds__(256) void k_prep(const int* __restrict__ adj,
                                              const float* __restrict__ Wh,
                                              const float* __restrict__ Wo,
                                              unsigned char* __restrict__ Mbyte,
                                              _Float16* __restrict__ wt1,
                                              _Float16* __restrict__ wt2) {
    const int bb = blockIdx.x, t = threadIdx.x;
    if (bb < 128) {
        int w = bb * 256 + t;                  // 32768 threads x 32 elements
        const int* p = adj + (size_t)w * 32;
        unsigned r[8];
#pragma unroll
        for (int q = 0; q < 8; q++) {
            int4 a = ((const int4*)p)[q];
            r[q] = (a.x > 0 ? 1u : 0u) | (a.y > 0 ? 1u << 8 : 0u) |
                   (a.z > 0 ? 1u << 16 : 0u) | (a.w > 0 ? 1u << 24 : 0u);
        }
        uint4* dst = (uint4*)(Mbyte + (size_t)w * 32);
        dst[0] = (uint4){r[0], r[1], r[2], r[3]};
        dst[1] = (uint4){r[4], r[5], r[6], r[7]};
    } else if (bb < 132) {
        const int row = (bb - 128) * 64 + (t >> 2);   // 0..255 = h*64+o
        const int kq = t & 3;
        const float* src = Wh + (size_t)(row >> 6) * 4096 + (row & 63);
#pragma unroll
        for (int kk = 0; kk < 16; kk += 8) {
            const int k0 = kq * 16 + kk;
            union { half8 v; cvt2_t c[4]; } pk_;
#pragma unroll
            for (int j = 0; j < 8; j += 2)
                pk_.c[j >> 1] = __builtin_amdgcn_cvt_pkrtz(src[(k0 + j) * 64],
                                                           src[(k0 + j + 1) * 64]);
            *(half8*)(wt1 + (size_t)row * 64 + k0) = pk_.v;
        }
    } else {
        const int o = (bb - 132) * 16 + (t >> 4);     // 0..63
        const int k0 = (t & 15) * 16;
        const float* src = Wo + o;
#pragma unroll
        for (int kk = 0; kk < 16; kk += 8) {
            union { half8 v; cvt2_t c[4]; } pk_;
#pragma unroll
            for (int j = 0; j < 8; j += 2)
                pk_.c[j >> 1] = __builtin_amdgcn_cvt_pkrtz(src[(k0 + kk + j) * 64],
                                                           src[(k0 + kk + j + 1) * 64]);
            *(half8*)(wt2 + (size_t)o * 256 + k0 + kk) = pk_.v;
        }
    }
}

// ---------------- K1: layer-1 projection via fp16 MFMA (4 heads fused) ----------------
__global__ __launch_bounds__(512, 2) void k_proj1(const float* __restrict__ x,
                                                  const _Float16* __restrict__ wt1,
                                                  const float* __restrict__ ah,
                                                  _Float16* __restrict__ H1T,
                                                  float* __restrict__ F1,
                                                  float* __restrict__ F2) {
    __shared__ _Float16 xs[128][64];   // XOR-swizzled 16B units
    const int t = threadIdx.x;
    const int nb = blockIdx.x, g = blockIdx.y;
    const int n0 = nb * 128;
    const int b = g >> 4, tstep = g & 15;

    {   // stage x tile
        const int r = t >> 2, cq = t & 3;
        const float* xr = x + (((size_t)(b * 17 + tstep) * N_NODES + n0 + r) * FDIM) + cq * 16;
        float4 v0 = *(const float4*)(xr);
        float4 v1 = *(const float4*)(xr + 4);
        float4 v2 = *(const float4*)(xr + 8);
        float4 v3 = *(const float4*)(xr + 12);
        union { half8 v; cvt2_t c[4]; } u0, u1;
        u0.c[0] = __builtin_amdgcn_cvt_pkrtz(v0.x, v0.y);
        u0.c[1] = __builtin_amdgcn_cvt_pkrtz(v0.z, v0.w);
        u0.c[2] = __builtin_amdgcn_cvt_pkrtz(v1.x, v1.y);
        u0.c[3] = __builtin_amdgcn_cvt_pkrtz(v1.z, v1.w);
        u1.c[0] = __builtin_amdgcn_cvt_pkrtz(v2.x, v2.y);
        u1.c[1] = __builtin_amdgcn_cvt_pkrtz(v2.z, v2.w);
        u1.c[2] = __builtin_amdgcn_cvt_pkrtz(v3.x, v3.y);
        u1.c[3] = __builtin_amdgcn_cvt_pkrtz(v3.z, v3.w);
        *(half8*)&xs[r][((2 * cq) ^ (r & 7)) * 8] = u0.v;
        *(half8*)&xs[r][((2 * cq + 1) ^ (r & 7)) * 8] = u1.v;
    }
    __syncthreads();

    const int wv = t >> 6, ln = t & 63, li = ln & 15, grp = ln >> 4;
    const int arow = wv * 16 + li;

    f32x4 acc[16];
#pragma unroll
    for (int q = 0; q < 16; q++) acc[q] = (f32x4){0.f, 0.f, 0.f, 0.f};

#pragma unroll
    for (int s = 0; s < 2; s++) {
        half8 af = *(const half8*)&xs[arow][((s * 4 + grp) ^ (arow & 7)) * 8];
#pragma unroll
        for (int tile = 0; tile < 16; tile++) {
            half8 bf = *(const half8*)(wt1 + (size_t)(tile * 16 + li) * 64 + s * 32 + grp * 8);
            acc[tile] = __builtin_amdgcn_mfma_f32_16x16x32_f16(af, bf, acc[tile], 0, 0, 0);
        }
    }

    const int nbase = n0 + wv * 16 + grp * 4;
#pragma unroll
    for (int h = 0; h < 4; h++) {
        float p1[4] = {0.f, 0.f, 0.f, 0.f}, p2[4] = {0.f, 0.f, 0.f, 0.f};
#pragma unroll
        for (int ot = 0; ot < 4; ot++) {
            float a1v = ah[h * 128 + ot * 16 + li];
            float a2v = ah[h * 128 + 64 + ot * 16 + li];
            f32x4 A = acc[h * 4 + ot];
#pragma unroll
            for (int r = 0; r < 4; r++) {
                p1[r] = fmaf(A[r], a1v, p1[r]);
                p2[r] = fmaf(A[r], a2v, p2[r]);
            }
        }
#pragma unroll
        for (int m = 1; m < 16; m <<= 1)
#pragma unroll
            for (int r = 0; r < 4; r++) {
                p1[r] += __shfl_xor(p1[r], m);
                p2[r] += __shfl_xor(p2[r], m);
            }
        if (li == 0) {
            const size_t gh = (size_t)h * NG + g;
#pragma unroll
            for (int r = 0; r < 4; r++) {
                F1[gh * N_NODES + nbase + r] = p1[r] * LOG2E;
                F2[gh * N_NODES + nbase + r] = p2[r] * LOG2E;
            }
        }
    }
#pragma unroll
    for (int tile = 0; tile < 16; tile++) {
        const int h = tile >> 2, ot = tile & 3;
        union { half4 v; cvt2_t c[2]; } st;
        st.c[0] = __builtin_amdgcn_cvt_pkrtz(acc[tile][0], acc[tile][1]);
        st.c[1] = __builtin_amdgcn_cvt_pkrtz(acc[tile][2], acc[tile][3]);
        _Float16* dst = H1T + (((size_t)h * NG + g) * FDIM + ot * 16 + li) * N_NODES + nbase;
        *(half4*)dst = st.v;
    }
}

// ---------------- fused masked attention (fp16, byte mask, deep prefetch) ----------------
// 128 rows/block, 8 waves; j-tile 256 double-buffered LDS (XOR-swizzled);
// mask = uchar {0,1}, per-jt reg double-buffer (issued 1 jt ahead);
// f2s LDS read rotated 1 jc ahead; multiplicative mask after exp2;
// row-sum via ones-MFMA; 1 barrier per jt.
template<int CONCAT>
__global__ __launch_bounds__(512, 4) void k_attn(
    const _Float16* __restrict__ HT,         // [G][64 f][1024 n] f16
    const float* __restrict__ F1,            // [G][1024] (×log2e)
    const float* __restrict__ F2,
    const unsigned char* __restrict__ Mb,    // [1024][1024] byte mask {0,1}
    _Float16* __restrict__ HC,               // concat out (CONCAT=1)
    float* __restrict__ out)                 // final out (CONCAT=0)
{
    __shared__ _Float16 vt[2][64][256];      // 64KB double buffer
    __shared__ float f2s[N_NODES];
    const int t = threadIdx.x;
    const int g = blockIdx.x, h = blockIdx.y, nb = blockIdx.z;
    const int i0 = nb * 128;
    const size_t gidx = CONCAT ? ((size_t)h * NG + g) : (size_t)g;

    ((float2*)f2s)[t] = ((const float2*)(F2 + gidx * N_NODES))[t];

    const int wv = t >> 6, ln = t & 63;
    const int li = ln & 15, grp = ln >> 4, jb = grp * 8;
    const int lx = li & 7;
    const int il = wv * 16 + li;
    const float f1v = F1[gidx * N_NODES + i0 + il];

    const _Float16* Hg = HT + gidx * (size_t)(FDIM * N_NODES);
    const int srow = wv * 8 + (ln >> 3);          // staging row (f)
    const int swu = (ln & 7) ^ (srow & 7);        // swizzled low-3 unit
    const _Float16* srcb = Hg + (size_t)srow * N_NODES + (ln & 7) * 8;
    const unsigned char* Mrow = Mb + (size_t)(i0 + il) * N_NODES + jb;

    f32x4 acc[4], acc5;
#pragma unroll
    for (int q = 0; q < 4; q++) acc[q] = (f32x4){0.f, 0.f, 0.f, 0.f};
    acc5 = (f32x4){0.f, 0.f, 0.f, 0.f};

    union { half8 v; unsigned short s[8]; } onesu;
#pragma unroll
    for (int q = 0; q < 8; q++) onesu.s[q] = 0x3C00;   // fp16 1.0
    const half8 ones = onesu.v;

    half8 stg[4];
    uint2 mbuf[2][8];                              // per-jt mask, double-buffered
    // prologue: buf0 <- jt0 V; stg <- jt1 V; mbuf[0] <- jt0 mask
#pragma unroll
    for (int k2 = 0; k2 < 4; k2++) stg[k2] = *(const half8*)(srcb + k2 * 64);
#pragma unroll
    for (int k2 = 0; k2 < 4; k2++)
        *(half8*)&vt[0][srow][(k2 * 8 + swu) * 8] = stg[k2];
#pragma unroll
    for (int k2 = 0; k2 < 4; k2++) stg[k2] = *(const half8*)(srcb + 256 + k2 * 64);
#pragma unroll
    for (int q = 0; q < 8; q++) mbuf[0][q] = *(const uint2*)(Mrow + q * 32);
    __syncthreads();                               // buf0 + f2s ready

    const float* f2p = &f2s[jb];
    float4 fa = *(const float4*)f2p;
    float4 fb = *(const float4*)(f2p + 4);

#pragma unroll
    for (int jt = 0; jt < 4; jt++) {
        if (jt < 3) {                              // write next V buf (overlaps compute)
#pragma unroll
            for (int k2 = 0; k2 < 4; k2++)
                *(half8*)&vt[(jt + 1) & 1][srow][(k2 * 8 + swu) * 8] = stg[k2];
            // prefetch next jt's mask (2400cy slack)
#pragma unroll
            for (int q = 0; q < 8; q++)
                mbuf[(jt + 1) & 1][q] = *(const uint2*)(Mrow + (jt + 1) * 256 + q * 32);
        }
        if (jt < 2) {                              // issue jt+2 V loads
#pragma unroll
            for (int k2 = 0; k2 < 4; k2++)
                stg[k2] = *(const half8*)(srcb + (jt + 2) * 256 + k2 * 64);
        }

#pragma unroll
        for (int jc = 0; jc < 8; jc++) {
            const uint2 w = mbuf[jt & 1][jc];
            const float4 cfa = fa, cfb = fb;
            if (!(jt == 3 && jc == 7)) {           // rotate f2 one jc ahead
                fa = *(const float4*)(f2p + 32);
                fb = *(const float4*)(f2p + 36);
            }
            f2p += 32;

            float b0 = (float)(unsigned char)(w.x);
            float b1 = (float)(unsigned char)(w.x >> 8);
            float b2 = (float)(unsigned char)(w.x >> 16);
            float b3 = (float)(w.x >> 24);
            float b4 = (float)(unsigned char)(w.y);
            float b5 = (float)(unsigned char)(w.y >> 8);
            float b6 = (float)(unsigned char)(w.y >> 16);
            float b7 = (float)(w.y >> 24);

            union { half8 v; cvt2_t c[4]; } afr;
            float s0, s1, p0, p1;
            s0 = f1v + cfa.x; s1 = f1v + cfa.y;
            s0 = fmaxf(s0, 0.2f * s0); s1 = fmaxf(s1, 0.2f * s1);
            p0 = __builtin_amdgcn_exp2f(s0) * b0;
            p1 = __builtin_amdgcn_exp2f(s1) * b1;
            afr.c[0] = __builtin_amdgcn_cvt_pkrtz(p0, p1);
            s0 = f1v + cfa.z; s1 = f1v + cfa.w;
            s0 = fmaxf(s0, 0.2f * s0); s1 = fmaxf(s1, 0.2f * s1);
            p0 = __builtin_amdgcn_exp2f(s0) * b2;
            p1 = __builtin_amdgcn_exp2f(s1) * b3;
            afr.c[1] = __builtin_amdgcn_cvt_pkrtz(p0, p1);
            s0 = f1v + cfb.x; s1 = f1v + cfb.y;
            s0 = fmaxf(s0, 0.2f * s0); s1 = fmaxf(s1, 0.2f * s1);
            p0 = __builtin_amdgcn_exp2f(s0) * b4;
            p1 = __builtin_amdgcn_exp2f(s1) * b5;
            afr.c[2] = __builtin_amdgcn_cvt_pkrtz(p0, p1);
            s0 = f1v + cfb.z; s1 = f1v + cfb.w;
            s0 = fmaxf(s0, 0.2f * s0); s1 = fmaxf(s1, 0.2f * s1);
            p0 = __builtin_amdgcn_exp2f(s0) * b6;
            p1 = __builtin_amdgcn_exp2f(s1) * b7;
            afr.c[3] = __builtin_amdgcn_cvt_pkrtz(p0, p1);

            const int ub = (jc >> 1) * 8 + (((jc & 1) * 4 + grp) ^ lx);
#pragma unroll
            for (int q = 0; q < 4; q++) {
                half8 bfr = *(const half8*)&vt[jt & 1][q * 16 + li][ub * 8];
                acc[q] = __builtin_amdgcn_mfma_f32_16x16x32_f16(afr.v, bfr, acc[q], 0, 0, 0);
            }
            acc5 = __builtin_amdgcn_mfma_f32_16x16x32_f16(afr.v, ones, acc5, 0, 0, 0);
        }
        if (jt < 3) __syncthreads();               // single barrier per jt
    }

    float rin[4];
#pragma unroll
    for (int r2 = 0; r2 < 4; r2++) rin[r2] = 1.0f / acc5[r2];

    if (CONCAT) {
        _Float16* HCg = HC + (size_t)g * N_NODES * 256 + h * 64;
#pragma unroll
        for (int q = 0; q < 4; q++)
#pragma unroll
            for (int r2 = 0; r2 < 4; r2++) {
                int irow = wv * 16 + grp * 4 + r2;
                float v = acc[q][r2] * rin[r2];
                v = v > 0.f ? v : expm1f(v); // ELU
                HCg[(size_t)(i0 + irow) * 256 + q * 16 + li] = (_Float16)v;
            }
    } else {
        float* og = out + (size_t)g * N_NODES * FDIM;
#pragma unroll
        for (int q = 0; q < 4; q++)
#pragma unroll
            for (int r2 = 0; r2 < 4; r2++) {
                int irow = wv * 16 + grp * 4 + r2;
                float v = acc[q][r2] * rin[r2];
                og[(size_t)(i0 + irow) * FDIM + q * 16 + li] = v > 0.f ? v : 0.f;
            }
    }
}

// ---------------- K3: layer-2 projection via fp16 MFMA ----------------
__global__ __launch_bounds__(512, 2) void k_proj2(const _Float16* __restrict__ HC,
                                                  const _Float16* __restrict__ wt2,
                                                  const float* __restrict__ ao,
                                                  _Float16* __restrict__ H2T,
                                                  float* __restrict__ F1b,
                                                  float* __restrict__ F2b) {
    __shared__ _Float16 xs[128][256];  // 64KB, XOR-swizzled within 8-unit groups
    const int t = threadIdx.x;
    const int nb = blockIdx.x, g = blockIdx.y;
    const int n0 = nb * 128;

    {   // stage HC tile
        const int r = t >> 2, cq = t & 3;
        const _Float16* src = HC + ((size_t)g * N_NODES + n0 + r) * 256 + cq * 64;
#pragma unroll
        for (int uu = 0; uu < 8; uu++) {
            int u = cq * 8 + uu;
            half8 v = *(const half8*)(src + uu * 8);
            int us = (u & 24) | ((u ^ r) & 7);
            *(half8*)&xs[r][us * 8] = v;
        }
    }
    __syncthreads();

    const int wv = t >> 6, ln = t & 63, li = ln & 15, grp = ln >> 4;
    const int arow = wv * 16 + li;

    f32x4 acc[4];
#pragma unroll
    for (int q = 0; q < 4; q++) acc[q] = (f32x4){0.f, 0.f, 0.f, 0.f};

#pragma unroll
    for (int s = 0; s < 8; s++) {
        int u = s * 4 + grp;
        int us = (u & 24) | ((u ^ arow) & 7);
        half8 af = *(const half8*)&xs[arow][us * 8];
#pragma unroll
        for (int tile = 0; tile < 4; tile++) {
            half8 bf = *(const half8*)(wt2 + (size_t)(tile * 16 + li) * 256 + s * 32 + grp * 8);
            acc[tile] = __builtin_amdgcn_mfma_f32_16x16x32_f16(af, bf, acc[tile], 0, 0, 0);
        }
    }

    const int nbase = n0 + wv * 16 + grp * 4;
    {
        float p1[4] = {0.f, 0.f, 0.f, 0.f}, p2[4] = {0.f, 0.f, 0.f, 0.f};
#pragma unroll
        for (int ot = 0; ot < 4; ot++) {
            float a1v = ao[ot * 16 + li];
            float a2v = ao[64 + ot * 16 + li];
            f32x4 A = acc[ot];
#pragma unroll
            for (int r = 0; r < 4; r++) {
                p1[r] = fmaf(A[r], a1v, p1[r]);
                p2[r] = fmaf(A[r], a2v, p2[r]);
            }
        }
#pragma unroll
        for (int m = 1; m < 16; m <<= 1)
#pragma unroll
            for (int r = 0; r < 4; r++) {
                p1[r] += __shfl_xor(p1[r], m);
                p2[r] += __shfl_xor(p2[r], m);
            }
        if (li == 0) {
#pragma unroll
            for (int r = 0; r < 4; r++) {
                F1b[(size_t)g * N_NODES + nbase + r] = p1[r] * LOG2E;
                F2b[(size_t)g * N_NODES + nbase + r] = p2[r] * LOG2E;
            }
        }
    }
#pragma unroll
    for (int tile = 0; tile < 4; tile++) {
        union { half4 v; cvt2_t c[2]; } st;
        st.c[0] = __builtin_amdgcn_cvt_pkrtz(acc[tile][0], acc[tile][1]);
        st.c[1] = __builtin_amdgcn_cvt_pkrtz(acc[tile][2], acc[tile][3]);
        _Float16* dst = H2T + ((size_t)g * FDIM + tile * 16 + li) * N_NODES + nbase;
        *(half4*)dst = st.v;
    }
}

extern "C" void kernel_launch(void* const* d_in, const int* in_sizes, int n_in,
                              void* d_out, int out_size, void* d_ws, size_t ws_size,
                              hipStream_t stream) {
    const float* x  = (const float*)d_in[0];
    const int* adj  = (const int*)d_in[1];
    const float* Wh = (const float*)d_in[2];
    const float* ah = (const float*)d_in[3];
    const float* Wo = (const float*)d_in[4];
    const float* ao = (const float*)d_in[5];

    char* ws = (char*)d_ws;
    unsigned char* Mbyte = (unsigned char*)(ws);             // 1 MB
    _Float16* wt1 = (_Float16*)(ws + 1048576);               // 32 KB
    _Float16* wt2 = (_Float16*)(ws + 1081344);               // 32 KB
    float* F1  = (float*)(ws + 1114112);                     // 512 KB
    float* F2  = (float*)(ws + 1638400);                     // 512 KB
    float* F1b = (float*)(ws + 2162688);                     // 128 KB
    float* F2b = (float*)(ws + 2293760);                     // 128 KB
    _Float16* H1T = (_Float16*)(ws + 2424832);               // 16 MB
    _Float16* HC  = (_Float16*)(ws + 2424832 + 16777216);    // 16 MB
    _Float16* H2T = (_Float16*)(ws + 2424832 + 33554432);    //  4 MB
    float* out = (float*)d_out;

    k_prep   <<<dim3(136),       dim3(256), 0, stream>>>(adj, Wh, Wo, Mbyte, wt1, wt2);
    k_proj1  <<<dim3(8, 32),     dim3(512), 0, stream>>>(x, wt1, ah, H1T, F1, F2);
    k_attn<1><<<dim3(32, 4, 8),  dim3(512), 0, stream>>>(H1T, F1, F2, Mbyte, HC, nullptr);
    k_proj2  <<<dim3(8, 32),     dim3(512), 0, stream>>>(HC, wt2, ao, H2T, F1b, F2b);
    k_attn<0><<<dim3(32, 1, 8),  dim3(512), 0, stream>>>(H2T, F1b, F2b, Mbyte, nullptr, out);
}